// Round 1
// baseline (3299.359 us; speedup 1.0000x reference)
//
#include <hip/hip_runtime.h>

// ---------------------------------------------------------------------------
// LSTM layer, T=512 B=64 D=H=1024, out = h_T (64x1024 fp32).
// Round 6: tag-in-data h exchange -> single L3 round trip per step.
//   - h exchanged as bf16 pairs per dword; LSB of the LOW bf16 carries a
//     1-bit step tag ((t>>1)&1). Consumers load fragments directly from
//     global (row-major pairs ARE the 16x16x32 A-fragment) and retry until
//     all 16 dwords/lane carry the expected tag. No flags, no producer
//     vmcnt drain, no Hs LDS staging, no syncB (gl double-buffered).
//   - double-buffered hq slots + 1-bit tag are sufficient: h_{t+2} can only
//     overwrite h_t after every block gathered h_{t+1} (which requires all
//     blocks done with h_t); h_{t-4} is visible-overwritten because each
//     thread's own gather vmcnt(0) drains its prior h stores.
//   - numerics: half the exchanged h values rounded to the forced-LSB bf16
//     grid (<=1 ulp vs <=0.5 ulp RNE). Fallback if absmax fails: exact
//     [bf16|tag16] 32-bit exchange (2x gather traffic).
//   - next levers if still latency-bound: pipelined double-attempt gather
//     (halves retry quantization), gate compute split across 512 threads.
// ---------------------------------------------------------------------------

typedef __attribute__((ext_vector_type(8))) short     short8;   // 8 bf16 (4 VGPR)
typedef __attribute__((ext_vector_type(4))) float     f32x4;
typedef __attribute__((ext_vector_type(8))) unsigned short ushort8v;
typedef __attribute__((ext_vector_type(4))) unsigned short ushort4v;
typedef __attribute__((ext_vector_type(4))) unsigned int   uint4v;

__device__ __forceinline__ unsigned short f2bf(float f) {
  unsigned int u = __float_as_uint(f);
  u += 0x7FFFu + ((u >> 16) & 1u);          // RNE
  return (unsigned short)(u >> 16);
}

// round-to-nearest bf16 on the grid {LSB == tag}; |err| <= 1 ulp
__device__ __forceinline__ unsigned int bf_tag(float f, unsigned int tag) {
  unsigned int a = __float_as_uint(f) >> 16;
  a += (a ^ tag) & 1u;                      // bump to nearest pattern w/ LSB==tag
  return a & 0xFFFFu;
}

__device__ __forceinline__ void dma16(const void* g, void* l) {
  __builtin_amdgcn_global_load_lds(
      (const __attribute__((address_space(1))) unsigned int*)g,
      (__attribute__((address_space(3))) unsigned int*)l, 16, 0, 0);
}

__device__ __forceinline__ float sig2(float x) {   // = (tanh(x)+1)/2 = sigma(2x)
  return __builtin_amdgcn_rcpf(1.f + __expf(-2.f * x));
}

// ---------------- prep 1: cast x -> bf16; init tagged h buffers -------------
__global__ void k_cast_x(const float* __restrict__ x, unsigned short* __restrict__ xb,
                         unsigned int* __restrict__ hq) {
  long i = ((long)blockIdx.x * 256 + threadIdx.x) * 8;
  f32x4 a = *(const f32x4*)(x + i);
  f32x4 b = *(const f32x4*)(x + i + 4);
  ushort8v o;
  o[0] = f2bf(a[0]); o[1] = f2bf(a[1]); o[2] = f2bf(a[2]); o[3] = f2bf(a[3]);
  o[4] = f2bf(b[0]); o[5] = f2bf(b[1]); o[6] = f2bf(b[2]); o[7] = f2bf(b[3]);
  *(ushort8v*)(xb + i) = o;
  // init all 65536 hq dwords with low-bf16 LSB = 1 (mismatches tag(t=0..1)=0)
  if (blockIdx.x < 256) hq[(blockIdx.x << 8) + threadIdx.x] = 0x00010001u;
}

// ---------------- prep 2: transpose-cast 8 x (1024x1024 fp32 -> [n][k] bf16)
__global__ void k_tcast8(const float* __restrict__ s0, const float* __restrict__ s1,
                         const float* __restrict__ s2, const float* __restrict__ s3,
                         const float* __restrict__ s4, const float* __restrict__ s5,
                         const float* __restrict__ s6, const float* __restrict__ s7,
                         unsigned short* __restrict__ dstBase) {
  __shared__ unsigned short tile[64][65];
  const int z = blockIdx.z;
  const float* src = (z == 0) ? s0 : (z == 1) ? s1 : (z == 2) ? s2 : (z == 3) ? s3
                   : (z == 4) ? s4 : (z == 5) ? s5 : (z == 6) ? s6 : s7;
  unsigned short* dst = dstBase + (size_t)z * 1048576;
  const int k0 = blockIdx.x << 6;
  const int n0 = blockIdx.y << 6;
  const int tid = threadIdx.x;
#pragma unroll
  for (int i = 0; i < 4; ++i) {
    int q = tid + (i << 8);
    int r = q >> 4, c4 = (q & 15) << 2;
    f32x4 v = *(const f32x4*)(src + (size_t)(k0 + r) * 1024 + n0 + c4);
    tile[r][c4 + 0] = f2bf(v[0]);
    tile[r][c4 + 1] = f2bf(v[1]);
    tile[r][c4 + 2] = f2bf(v[2]);
    tile[r][c4 + 3] = f2bf(v[3]);
  }
  __syncthreads();
#pragma unroll
  for (int i = 0; i < 4; ++i) {
    int q = tid + (i << 8);
    int rn = q >> 4, kc = (q & 15) << 2;
    ushort4v o;
    o[0] = tile[kc + 0][rn];
    o[1] = tile[kc + 1][rn];
    o[2] = tile[kc + 2][rn];
    o[3] = tile[kc + 3][rn];
    *(ushort4v*)(dst + (size_t)(n0 + rn) * 1024 + k0 + kc) = o;
  }
}

// gather one attempt: 4 fragment dwordx4 (chunks K = wv+8*j4), coherent
#define GATHER_NOWAIT(F0, F1, F2, F3, PB)                                \
  asm volatile(                                                          \
      "global_load_dwordx4 %0, %4, off sc0 sc1\n\t"                      \
      "global_load_dwordx4 %1, %4, off offset:512 sc0 sc1\n\t"           \
      "global_load_dwordx4 %2, %4, off offset:1024 sc0 sc1\n\t"          \
      "global_load_dwordx4 %3, %4, off offset:1536 sc0 sc1"              \
      : "=&v"(F0), "=&v"(F1), "=&v"(F2), "=&v"(F3)                       \
      : "v"(PB) : "memory")

#define GATHER_WAIT(F0, F1, F2, F3, PB)                                  \
  asm volatile(                                                          \
      "global_load_dwordx4 %0, %4, off sc0 sc1\n\t"                      \
      "global_load_dwordx4 %1, %4, off offset:512 sc0 sc1\n\t"           \
      "global_load_dwordx4 %2, %4, off offset:1024 sc0 sc1\n\t"          \
      "global_load_dwordx4 %3, %4, off offset:1536 sc0 sc1\n\t"          \
      "s_waitcnt vmcnt(0)"                                               \
      : "=&v"(F0), "=&v"(F1), "=&v"(F2), "=&v"(F3)                       \
      : "v"(PB) : "memory")

#define TAGBAD(F0, F1, F2, F3, TM)                                       \
  ((((F0)[0]^(TM))|((F0)[1]^(TM))|((F0)[2]^(TM))|((F0)[3]^(TM))|         \
    ((F1)[0]^(TM))|((F1)[1]^(TM))|((F1)[2]^(TM))|((F1)[3]^(TM))|         \
    ((F2)[0]^(TM))|((F2)[1]^(TM))|((F2)[2]^(TM))|((F2)[3]^(TM))|         \
    ((F3)[0]^(TM))|((F3)[1]^(TM))|((F3)[2]^(TM))|((F3)[3]^(TM))) & 1u)

// ---------------- main: persistent recurrence -------------------------------
__global__ __launch_bounds__(512, 2) void k_lstm(
    const unsigned short* __restrict__ xb,    // [512*64][1024] bf16
    const unsigned short* __restrict__ WtT,   // [4096][1024] bf16, n = gate*1024+u
    const unsigned short* __restrict__ RtT,
    const float* __restrict__ b_i, const float* __restrict__ b_f,
    const float* __restrict__ b_o, const float* __restrict__ b_c,
    const float* __restrict__ s0, const float* __restrict__ c0,
    unsigned int* __restrict__ hq,            // [4 bg][2 buf][16 row][512] dwords
    float* __restrict__ out) {
  __shared__ __align__(16) unsigned short Xs[2][16384];   // 2 x 32 KB
  __shared__ float gl[2][8192];                           // 2 x 32 KB

  const int tid = threadIdx.x;
  const int bid = blockIdx.x;                 // 256 blocks = 4 bg x 64 cs
  const int cs = bid & 63;
  const int bg = bid >> 6;
  const int u0 = cs << 4;                     // 16 units
  const int b0 = bg << 4;                     // 16 batch rows
  const int wv = tid >> 6, ln = tid & 63;
  const int qd = ln >> 4, nc = ln & 15;
  const int grow = ln >> 2;                   // 0..15 (row for x-DMA)
  const int gsub = ln & 3;                    // 0..3  (global octet)
  const int gsx = gsub ^ (grow & 3);          // swizzled octet (Xs layout)

  // ---- weights: wave wv owns chunks K = j4*8 + wv, ALL 4 gates ----
  short8 wfr[4][4], rfr[4][4];
#pragma unroll
  for (int j4 = 0; j4 < 4; ++j4) {
    const int K = (j4 << 3) + wv;
#pragma unroll
    for (int g = 0; g < 4; ++g) {
      const size_t off = ((size_t)((g << 10) + u0 + nc) << 10) + (K << 5) + (qd << 3);
      wfr[j4][g] = *(const short8*)(WtT + off);
      rfr[j4][g] = *(const short8*)(RtT + off);
    }
  }

  // ---- per-thread state (tid<256): cell (m, un) ----
  const int m = tid >> 4, un = tid & 15;
  const int gio = (b0 + m) * 1024 + u0 + un;
  float c = 0.f, bi = 0.f, bff = 0.f, bo = 0.f, bc = 0.f;
  const int hq_bg = bg << 14;                 // dword base of this group's region
  if (tid < 256) {
    c = c0[gio];
    bi = b_i[u0 + un]; bff = b_f[u0 + un]; bo = b_o[u0 + un]; bc = b_c[u0 + un];
    float h0 = s0[gio];
    float hp = __shfl_xor(h0, 1);
    if (!(tid & 1)) {                         // publish h_0 with tag 0
      unsigned int wd = bf_tag(h0, 0u) | ((unsigned int)f2bf(hp) << 16);
      __hip_atomic_store(&hq[hq_bg + (m << 9) + ((u0 + un) >> 1)], wd,
                         __ATOMIC_RELAXED, __HIP_MEMORY_SCOPE_AGENT);
    }
  }
  // ---- stage x_0 (wave-private chunks; lds base is wave-uniform) ----
#pragma unroll
  for (int j4 = 0; j4 < 4; ++j4) {
    const int K = (j4 << 3) + wv;
    dma16(xb + (((size_t)(b0 + grow)) << 10) + (K << 5) + (gsx << 3), &Xs[0][K << 9]);
  }
  __syncthreads();                            // drains x0 DMA (local only)

  // per-lane fragment base: row nc, chunk wv(+8j4), octet qd
  const unsigned int* const pbE = hq + hq_bg + (nc << 9) + (wv << 4) + (qd << 2);
  const unsigned int* const pbO = pbE + 8192;

  for (int t = 0; t < 512; ++t) {
    f32x4 acc[4] = {{0.f,0.f,0.f,0.f},{0.f,0.f,0.f,0.f},{0.f,0.f,0.f,0.f},{0.f,0.f,0.f,0.f}};
    const unsigned int* pb = (t & 1) ? pbO : pbE;
    uint4v f0, f1, f2, f3;
    // ---- attempt-1 issue (no wait): latency hides under DMA issue + x-half --
    GATHER_NOWAIT(f0, f1, f2, f3, pb);
    // ---- issue x_{t+1} DMA ----
    {
      const int tn = (t + 1) & 511;
      const size_t xrow = (size_t)((tn << 6) + b0 + grow) << 10;
      unsigned short* xd = &Xs[(t + 1) & 1][0];
#pragma unroll
      for (int j4 = 0; j4 < 4; ++j4) {
        const int K = (j4 << 3) + wv;
        dma16(xb + xrow + (K << 5) + (gsx << 3), xd + (K << 9));
      }
    }
    // ---- x half (wave-private chunks) ----
    {
      const unsigned short* xsb = &Xs[t & 1][0];
#pragma unroll
      for (int j4 = 0; j4 < 4; ++j4) {
        const int K = (j4 << 3) + wv;
        short8 a = *(const short8*)(xsb + (K << 9) + (nc << 5) + ((qd ^ (nc & 3)) << 3));
#pragma unroll
        for (int g = 0; g < 4; ++g)
          acc[g] = __builtin_amdgcn_mfma_f32_16x16x32_bf16(a, wfr[j4][g], acc[g], 0, 0, 0);
      }
    }
    // ---- wait attempt-1 (also drains x-DMA), tag-check, retry ----
    const unsigned int tm = (unsigned int)((t >> 1) & 1);
    asm volatile("s_waitcnt vmcnt(0)"
                 : "+v"(f0), "+v"(f1), "+v"(f2), "+v"(f3) :: "memory");
    __builtin_amdgcn_sched_barrier(0);
    unsigned int bad = TAGBAD(f0, f1, f2, f3, tm);
    while (bad) {                             // per-lane divergent retry
      GATHER_WAIT(f0, f1, f2, f3, pb);
      __builtin_amdgcn_sched_barrier(0);
      bad = TAGBAD(f0, f1, f2, f3, tm);
    }
    // ---- h half: gathered dwords ARE the A-fragments ----
    {
      short8 a0 = __builtin_bit_cast(short8, f0);
      short8 a1 = __builtin_bit_cast(short8, f1);
      short8 a2 = __builtin_bit_cast(short8, f2);
      short8 a3 = __builtin_bit_cast(short8, f3);
#pragma unroll
      for (int g = 0; g < 4; ++g) {
        acc[g] = __builtin_amdgcn_mfma_f32_16x16x32_bf16(a0, rfr[0][g], acc[g], 0, 0, 0);
        acc[g] = __builtin_amdgcn_mfma_f32_16x16x32_bf16(a1, rfr[1][g], acc[g], 0, 0, 0);
        acc[g] = __builtin_amdgcn_mfma_f32_16x16x32_bf16(a2, rfr[2][g], acc[g], 0, 0, 0);
        acc[g] = __builtin_amdgcn_mfma_f32_16x16x32_bf16(a3, rfr[3][g], acc[g], 0, 0, 0);
      }
      float* glw = &gl[t & 1][wv << 10];
#pragma unroll
      for (int g = 0; g < 4; ++g)
#pragma unroll
        for (int rr = 0; rr < 4; ++rr)
          glw[(g << 8) + (((qd << 2) + rr) << 4) + nc] = acc[g][rr];
    }
    __syncthreads();                          // gl[t&1] ready (the only barrier)
    // ---- gates, state update, publish h_{t+1} (fire-and-forget) ----
    if (tid < 256) {
      float pi = bi, pf = bff, po = bo, pc = bc;
      const float* glb = &gl[t & 1][0];
#pragma unroll
      for (int w = 0; w < 8; ++w) {
        const float* glr = glb + (w << 10) + tid;
        pi += glr[0]; pf += glr[256]; po += glr[512]; pc += glr[768];
      }
      float it = sig2(pi), ft = sig2(pf), ot = sig2(po);
      float ch = 2.f * sig2(pc) - 1.f;
      c = ft * c + it * ch;
      float h = ot * (2.f * sig2(c) - 1.f);
      float hp = __shfl_xor(h, 1);
      if (!(tid & 1)) {
        unsigned int wd = bf_tag(h, (unsigned int)(((t + 1) >> 1) & 1)) |
                          ((unsigned int)f2bf(hp) << 16);
        __hip_atomic_store(&hq[hq_bg + (((t + 1) & 1) << 13) + (m << 9) + ((u0 + un) >> 1)],
                           wd, __ATOMIC_RELAXED, __HIP_MEMORY_SCOPE_AGENT);
      }
      if (t == 511) out[gio] = h;
    }
    // no syncB: gl is double-buffered; Xs/gl reuse ordering is enforced
    // transitively through the tag-gather handshake (see header comment)
  }
}

// ---------------------------------------------------------------------------
extern "C" void kernel_launch(void* const* d_in, const int* in_sizes, int n_in,
                              void* d_out, int out_size, void* d_ws, size_t ws_size,
                              hipStream_t stream) {
  const float* x   = (const float*)d_in[0];
  const float* W_i = (const float*)d_in[1];
  const float* W_f = (const float*)d_in[2];
  const float* W_c = (const float*)d_in[3];
  const float* W_o = (const float*)d_in[4];
  const float* R_i = (const float*)d_in[5];
  const float* R_f = (const float*)d_in[6];
  const float* R_c = (const float*)d_in[7];
  const float* R_o = (const float*)d_in[8];
  const float* b_i = (const float*)d_in[9];
  const float* b_f = (const float*)d_in[10];
  const float* b_c = (const float*)d_in[11];
  const float* b_o = (const float*)d_in[12];
  const float* s0  = (const float*)d_in[13];
  const float* c0  = (const float*)d_in[14];
  float* out = (float*)d_out;

  char* ws = (char*)d_ws;
  unsigned short* xb  = (unsigned short*)(ws);                               // 64 MB
  unsigned short* WtT = (unsigned short*)(ws + (size_t)67108864);            // 8 MB
  unsigned short* RtT = (unsigned short*)(ws + (size_t)67108864 + 8388608);  // 8 MB
  unsigned int*   hq  = (unsigned int*)(ws + (size_t)67108864 + 16777216);   // 256 KB

  k_cast_x<<<16384, 256, 0, stream>>>(x, xb, hq);
  // gate order i,f,o,c; z 0..3 -> W into WtT, z 4..7 -> R into RtT (contiguous)
  dim3 tg(16, 16, 8);
  k_tcast8<<<tg, 256, 0, stream>>>(W_i, W_f, W_o, W_c, R_i, R_f, R_o, R_c, WtT);

  k_lstm<<<256, 512, 0, stream>>>(xb, WtT, RtT, b_i, b_f, b_o, b_c, s0, c0,
                                  hq, out);
}

// Round 2
// 3104.827 us; speedup vs baseline: 1.0627x; 1.0627x over previous
//
#include <hip/hip_runtime.h>

// ---------------------------------------------------------------------------
// LSTM layer, T=512 B=64 D=H=1024, out = h_T (64x1024 fp32).
// Round 7: flag-poll exchange (round-5 protocol) + direct-fragment gather
// (round-6's one good idea), with the serial chain compressed:
//   - gather lands directly in MFMA A-fragment registers (no Hs LDS bounce)
//   - no syncB: gl double-buffered; producer waves 0-3 each drain their own
//     h stores (s_waitcnt vmcnt(0)) and flag-add themselves (4-way overlap
//     instead of block-barrier + single tid0 add)
//   - finer flags: keyed by cs&15 (4 blocks x 4 wave-adds = 16/step).
//     Consumer wave wv polls only its 2 producer flags {2wv, 2wv+1}
//     (8 blocks) instead of the whole 64-block group
//   - poll spins on a 4B flag with s_sleep(1) backoff (round-6 lesson:
//     NEVER spin on full-data coherent gathers - fabric congestion)
//   - gl writes XOR-swizzled (rr^qd) -> conflict-free; reads unchanged cost
// Safety without syncB (induction over the flag counts): poll(t) passing
// target 16(t+1) implies all 4 members of that flag group completed their
// step-(t-1) add; a block's syncA(t) requires all 8 waves' polls -> all 64
// group blocks completed step t-1 -> every gl[t&1] read (step t-2) and every
// h_{t-1} slot read precedes any step-t overwrite. Xs chunks are wave-private
// (written and read only by wave wv); each wave's gather vmcnt(0) drains its
// own x-DMA before the next step touches Xs.
// ---------------------------------------------------------------------------

typedef __attribute__((ext_vector_type(8))) short     short8;   // 8 bf16 (4 VGPR)
typedef __attribute__((ext_vector_type(4))) float     f32x4;
typedef __attribute__((ext_vector_type(8))) unsigned short ushort8v;
typedef __attribute__((ext_vector_type(4))) unsigned short ushort4v;
typedef __attribute__((ext_vector_type(4))) unsigned int   uint4v;

__device__ __forceinline__ unsigned short f2bf(float f) {
  unsigned int u = __float_as_uint(f);
  u += 0x7FFFu + ((u >> 16) & 1u);          // RNE
  return (unsigned short)(u >> 16);
}

__device__ __forceinline__ void dma16(const void* g, void* l) {
  __builtin_amdgcn_global_load_lds(
      (const __attribute__((address_space(1))) unsigned int*)g,
      (__attribute__((address_space(3))) unsigned int*)l, 16, 0, 0);
}

__device__ __forceinline__ float sig2(float x) {   // = (tanh(x)+1)/2 = sigma(2x)
  return __builtin_amdgcn_rcpf(1.f + __expf(-2.f * x));
}

// ---------------- prep 1: cast x -> bf16; zero flags ------------------------
__global__ void k_cast_x(const float* __restrict__ x, unsigned short* __restrict__ xb,
                         int* __restrict__ flags) {
  long i = ((long)blockIdx.x * 256 + threadIdx.x) * 8;
  f32x4 a = *(const f32x4*)(x + i);
  f32x4 b = *(const f32x4*)(x + i + 4);
  ushort8v o;
  o[0] = f2bf(a[0]); o[1] = f2bf(a[1]); o[2] = f2bf(a[2]); o[3] = f2bf(a[3]);
  o[4] = f2bf(b[0]); o[5] = f2bf(b[1]); o[6] = f2bf(b[2]); o[7] = f2bf(b[3]);
  *(ushort8v*)(xb + i) = o;
  if (blockIdx.x < 4) flags[(blockIdx.x << 8) + threadIdx.x] = 0;   // 1024 ints
}

// ---------------- prep 2: transpose-cast 8 x (1024x1024 fp32 -> [n][k] bf16)
__global__ void k_tcast8(const float* __restrict__ s0, const float* __restrict__ s1,
                         const float* __restrict__ s2, const float* __restrict__ s3,
                         const float* __restrict__ s4, const float* __restrict__ s5,
                         const float* __restrict__ s6, const float* __restrict__ s7,
                         unsigned short* __restrict__ dstBase) {
  __shared__ unsigned short tile[64][65];
  const int z = blockIdx.z;
  const float* src = (z == 0) ? s0 : (z == 1) ? s1 : (z == 2) ? s2 : (z == 3) ? s3
                   : (z == 4) ? s4 : (z == 5) ? s5 : (z == 6) ? s6 : s7;
  unsigned short* dst = dstBase + (size_t)z * 1048576;
  const int k0 = blockIdx.x << 6;
  const int n0 = blockIdx.y << 6;
  const int tid = threadIdx.x;
#pragma unroll
  for (int i = 0; i < 4; ++i) {
    int q = tid + (i << 8);
    int r = q >> 4, c4 = (q & 15) << 2;
    f32x4 v = *(const f32x4*)(src + (size_t)(k0 + r) * 1024 + n0 + c4);
    tile[r][c4 + 0] = f2bf(v[0]);
    tile[r][c4 + 1] = f2bf(v[1]);
    tile[r][c4 + 2] = f2bf(v[2]);
    tile[r][c4 + 3] = f2bf(v[3]);
  }
  __syncthreads();
#pragma unroll
  for (int i = 0; i < 4; ++i) {
    int q = tid + (i << 8);
    int rn = q >> 4, kc = (q & 15) << 2;
    ushort4v o;
    o[0] = tile[kc + 0][rn];
    o[1] = tile[kc + 1][rn];
    o[2] = tile[kc + 2][rn];
    o[3] = tile[kc + 3][rn];
    *(ushort4v*)(dst + (size_t)(n0 + rn) * 1024 + k0 + kc) = o;
  }
}

// coherent gather of 4 A-fragments (chunks K = wv+8*j4); final vmcnt(0) also
// drains this wave's x-DMA for t+1 (wave-private Xs chunks)
#define GATHER_WAIT(F0, F1, F2, F3, PB)                                  \
  asm volatile(                                                          \
      "global_load_dwordx4 %0, %4, off sc0 sc1\n\t"                      \
      "global_load_dwordx4 %1, %4, off offset:512 sc0 sc1\n\t"           \
      "global_load_dwordx4 %2, %4, off offset:1024 sc0 sc1\n\t"          \
      "global_load_dwordx4 %3, %4, off offset:1536 sc0 sc1\n\t"          \
      "s_waitcnt vmcnt(0)"                                               \
      : "=&v"(F0), "=&v"(F1), "=&v"(F2), "=&v"(F3)                       \
      : "v"(PB) : "memory")

// ---------------- main: persistent recurrence -------------------------------
__global__ __launch_bounds__(512, 2) void k_lstm(
    const unsigned short* __restrict__ xb,    // [512*64][1024] bf16
    const unsigned short* __restrict__ WtT,   // [4096][1024] bf16, n = gate*1024+u
    const unsigned short* __restrict__ RtT,
    const float* __restrict__ b_i, const float* __restrict__ b_f,
    const float* __restrict__ b_o, const float* __restrict__ b_c,
    const float* __restrict__ s0, const float* __restrict__ c0,
    unsigned int* __restrict__ hq,            // [4 bg][2 buf][16 row][512] dwords
    int* __restrict__ flags, float* __restrict__ out) {
  __shared__ __align__(16) unsigned short Xs[2][16384];   // 2 x 32 KB
  __shared__ __align__(16) float gl[2][8192];             // 2 x 32 KB

  const int tid = threadIdx.x;
  const int bid = blockIdx.x;                 // 256 blocks = 4 bg x 64 cs
  const int cs = bid & 63;
  const int bg = bid >> 6;
  const int u0 = cs << 4;                     // 16 units
  const int b0 = bg << 4;                     // 16 batch rows
  const int wv = tid >> 6, ln = tid & 63;
  const int qd = ln >> 4, nc = ln & 15;
  const int grow = ln >> 2;                   // 0..15 (row for x-DMA)
  const int gsub = ln & 3;                    // 0..3  (global octet)
  const int gsx = gsub ^ (grow & 3);          // swizzled octet (Xs layout)

  // ---- weights: wave wv owns chunks K = j4*8 + wv, ALL 4 gates ----
  short8 wfr[4][4], rfr[4][4];
#pragma unroll
  for (int j4 = 0; j4 < 4; ++j4) {
    const int K = (j4 << 3) + wv;
#pragma unroll
    for (int g = 0; g < 4; ++g) {
      const size_t off = ((size_t)((g << 10) + u0 + nc) << 10) + (K << 5) + (qd << 3);
      wfr[j4][g] = *(const short8*)(WtT + off);
      rfr[j4][g] = *(const short8*)(RtT + off);
    }
  }

  // ---- per-thread state (tid<256): cell (m, un) ----
  const int m = tid >> 4, un = tid & 15;
  const int gio = (b0 + m) * 1024 + u0 + un;
  float c = 0.f, bi = 0.f, bff = 0.f, bo = 0.f, bc = 0.f;
  const int hq_bg = bg << 14;                 // dword base of this group's region
  int* const myflag = &flags[((bg << 4) + (cs & 15)) << 4];   // 64B-padded
  if (tid < 256) {                            // waves 0..3 (wave-uniform branch)
    c = c0[gio];
    bi = b_i[u0 + un]; bff = b_f[u0 + un]; bo = b_o[u0 + un]; bc = b_c[u0 + un];
    float h0 = s0[gio];
    float hp = __shfl_xor(h0, 1);
    if (!(tid & 1)) {
      unsigned int wd = (unsigned int)f2bf(h0) | ((unsigned int)f2bf(hp) << 16);
      __hip_atomic_store(&hq[hq_bg + (m << 9) + ((u0 + un) >> 1)], wd,
                         __ATOMIC_RELAXED, __HIP_MEMORY_SCOPE_AGENT);
    }
    asm volatile("s_waitcnt vmcnt(0)" ::: "memory");          // own stores done
    if (ln == 0)
      __hip_atomic_fetch_add(myflag, 1, __ATOMIC_RELAXED, __HIP_MEMORY_SCOPE_AGENT);
  }
  // ---- stage x_0 (wave-private chunks; lds base is wave-uniform) ----
#pragma unroll
  for (int j4 = 0; j4 < 4; ++j4) {
    const int K = (j4 << 3) + wv;
    dma16(xb + (((size_t)(b0 + grow)) << 10) + (K << 5) + (gsx << 3), &Xs[0][K << 9]);
  }
  asm volatile("s_waitcnt vmcnt(0)" ::: "memory");            // x0 staged (wave-local)

  // per-lane fragment base: batch row nc, chunk wv(+8j4), octet qd
  const unsigned int* const pbE = hq + hq_bg + (nc << 9) + (wv << 4) + (qd << 2);
  const unsigned int* const pbO = pbE + 8192;
  // this wave's 2 producer flags: cs&15 in {2wv, 2wv+1}; lane parity splits
  int* const pollp = &flags[((bg << 4) + (wv << 1) + (ln & 1)) << 4];
  // gl swizzled read base (matches writer's rr^qd swizzle)
  const int rbase = (tid & 0xC0) + ((((tid >> 4) ^ (tid >> 6)) & 3) << 4) + (tid & 15);

  for (int t = 0; t < 512; ++t) {
    f32x4 acc[4] = {{0.f,0.f,0.f,0.f},{0.f,0.f,0.f,0.f},{0.f,0.f,0.f,0.f},{0.f,0.f,0.f,0.f}};
    // ---- x half (wave-private chunks) ----
    {
      const unsigned short* xsb = &Xs[t & 1][0];
#pragma unroll
      for (int j4 = 0; j4 < 4; ++j4) {
        const int K = (j4 << 3) + wv;
        short8 a = *(const short8*)(xsb + (K << 9) + (nc << 5) + ((qd ^ (nc & 3)) << 3));
#pragma unroll
        for (int g = 0; g < 4; ++g)
          acc[g] = __builtin_amdgcn_mfma_f32_16x16x32_bf16(a, wfr[j4][g], acc[g], 0, 0, 0);
      }
    }
    // ---- issue x_{t+1} DMA (drains at this step's gather vmcnt(0)) ----
    {
      const int tn = (t + 1) & 511;
      const size_t xrow = (size_t)((tn << 6) + b0 + grow) << 10;
      unsigned short* xd = &Xs[(t + 1) & 1][0];
#pragma unroll
      for (int j4 = 0; j4 < 4; ++j4) {
        const int K = (j4 << 3) + wv;
        dma16(xb + xrow + (K << 5) + (gsx << 3), xd + (K << 9));
      }
    }
    // ---- poll only THIS wave's 8 producer blocks (2 flags) ----
    {
      const int target = (t + 1) << 4;        // 16 wave-adds per flag per step
      while (__hip_atomic_load(pollp, __ATOMIC_RELAXED, __HIP_MEMORY_SCOPE_AGENT) < target)
        __builtin_amdgcn_s_sleep(1);
    }
    // ---- gather h_t directly as A-fragments (coherent, one trip) ----
    const unsigned int* pb = (t & 1) ? pbO : pbE;
    uint4v f0, f1, f2, f3;
    GATHER_WAIT(f0, f1, f2, f3, pb);
    // ---- h half ----
    {
      short8 a0 = __builtin_bit_cast(short8, f0);
      short8 a1 = __builtin_bit_cast(short8, f1);
      short8 a2 = __builtin_bit_cast(short8, f2);
      short8 a3 = __builtin_bit_cast(short8, f3);
#pragma unroll
      for (int g = 0; g < 4; ++g) {
        acc[g] = __builtin_amdgcn_mfma_f32_16x16x32_bf16(a0, rfr[0][g], acc[g], 0, 0, 0);
        acc[g] = __builtin_amdgcn_mfma_f32_16x16x32_bf16(a1, rfr[1][g], acc[g], 0, 0, 0);
        acc[g] = __builtin_amdgcn_mfma_f32_16x16x32_bf16(a2, rfr[2][g], acc[g], 0, 0, 0);
        acc[g] = __builtin_amdgcn_mfma_f32_16x16x32_bf16(a3, rfr[3][g], acc[g], 0, 0, 0);
      }
      float* glw = &gl[t & 1][wv << 10];
#pragma unroll
      for (int g = 0; g < 4; ++g)
#pragma unroll
        for (int rr = 0; rr < 4; ++rr)
          glw[(g << 8) + (qd << 6) + (((rr ^ qd) & 3) << 4) + nc] = acc[g][rr];
    }
    __syncthreads();                          // gl[t&1] ready (the only barrier)
    // ---- gates, state update, publish h_{t+1} (per-wave drain + signal) ----
    if (tid < 256) {
      float pi = bi, pfv = bff, po = bo, pc = bc;
      const float* glb = &gl[t & 1][rbase];
#pragma unroll
      for (int w = 0; w < 8; ++w) {
        const float* glr = glb + (w << 10);
        pi += glr[0]; pfv += glr[256]; po += glr[512]; pc += glr[768];
      }
      float it = sig2(pi), ft = sig2(pfv), ot = sig2(po);
      float ch = 2.f * sig2(pc) - 1.f;
      c = ft * c + it * ch;
      float h = ot * (2.f * sig2(c) - 1.f);
      if (t < 511) {
        float hp = __shfl_xor(h, 1);
        if (!(tid & 1)) {
          unsigned int wd = (unsigned int)f2bf(h) | ((unsigned int)f2bf(hp) << 16);
          __hip_atomic_store(&hq[hq_bg + (((t + 1) & 1) << 13) + (m << 9) + ((u0 + un) >> 1)],
                             wd, __ATOMIC_RELAXED, __HIP_MEMORY_SCOPE_AGENT);
        }
        asm volatile("s_waitcnt vmcnt(0)" ::: "memory");      // own stores done
        if (ln == 0)
          __hip_atomic_fetch_add(myflag, 1, __ATOMIC_RELAXED, __HIP_MEMORY_SCOPE_AGENT);
      } else {
        out[gio] = h;
      }
    }
    // no syncB: gl double-buffered; reuse ordering proven via flag induction
  }
}

// ---------------------------------------------------------------------------
extern "C" void kernel_launch(void* const* d_in, const int* in_sizes, int n_in,
                              void* d_out, int out_size, void* d_ws, size_t ws_size,
                              hipStream_t stream) {
  const float* x   = (const float*)d_in[0];
  const float* W_i = (const float*)d_in[1];
  const float* W_f = (const float*)d_in[2];
  const float* W_c = (const float*)d_in[3];
  const float* W_o = (const float*)d_in[4];
  const float* R_i = (const float*)d_in[5];
  const float* R_f = (const float*)d_in[6];
  const float* R_c = (const float*)d_in[7];
  const float* R_o = (const float*)d_in[8];
  const float* b_i = (const float*)d_in[9];
  const float* b_f = (const float*)d_in[10];
  const float* b_c = (const float*)d_in[11];
  const float* b_o = (const float*)d_in[12];
  const float* s0  = (const float*)d_in[13];
  const float* c0  = (const float*)d_in[14];
  float* out = (float*)d_out;

  char* ws = (char*)d_ws;
  unsigned short* xb  = (unsigned short*)(ws);                               // 64 MB
  unsigned short* WtT = (unsigned short*)(ws + (size_t)67108864);            // 8 MB
  unsigned short* RtT = (unsigned short*)(ws + (size_t)67108864 + 8388608);  // 8 MB
  unsigned int*   hq  = (unsigned int*)(ws + (size_t)67108864 + 16777216);   // 256 KB
  int* flags          = (int*)(ws + (size_t)67108864 + 16777216 + 262144);   // 4 KB

  k_cast_x<<<16384, 256, 0, stream>>>(x, xb, flags);
  // gate order i,f,o,c; z 0..3 -> W into WtT, z 4..7 -> R into RtT (contiguous)
  dim3 tg(16, 16, 8);
  k_tcast8<<<tg, 256, 0, stream>>>(W_i, W_f, W_o, W_c, R_i, R_f, R_o, R_c, WtT);

  k_lstm<<<256, 512, 0, stream>>>(xb, WtT, RtT, b_i, b_f, b_o, b_c, s0, c0,
                                  hq, flags, out);
}

// Round 3
// 1523.096 us; speedup vs baseline: 2.1662x; 2.0385x over previous
//
#include <hip/hip_runtime.h>

// ---------------------------------------------------------------------------
// LSTM layer, T=512 B=64 D=H=1024, out = h_T (64x1024 fp32).
// Round 8: round-5 skeleton (1224us, known-good) + three isolated changes.
//   KEPT from round 5 (load-bearing, do NOT touch):
//     - syncA (gl ready) + syncB (h-store drain) per step
//     - coarse flags: 8 per group, 128B apart, ONE tid0 add per block/step
//     - poll with s_sleep(1) on 4B flags; x-DMA issued before the poll
//   CHANGED (each verified in r6/r7 or provably equivalent):
//     1. gather lands directly in MFMA A-fragment registers (no Hs LDS
//        bounce; r7-verified lane mapping; -32KB LDS, fewer LDS ops/step)
//     2. gl writes XOR-swizzled (rr^qd): conflict-free stores (r5 was 4-way)
//     3. per-wave partial poll: lane polls flag (2wv+(ln&1))&7 only.
//        Block semantics identical (syncA joins all 8 waves -> block still
//        waits for all 8 flags), so the r5 overwrite-safety induction holds;
//        but each wave starts gather+h-MFMA as soon as ITS producers signal.
// ---------------------------------------------------------------------------

typedef __attribute__((ext_vector_type(8))) short     short8;   // 8 bf16 (4 VGPR)
typedef __attribute__((ext_vector_type(4))) float     f32x4;
typedef __attribute__((ext_vector_type(8))) unsigned short ushort8v;
typedef __attribute__((ext_vector_type(4))) unsigned short ushort4v;
typedef __attribute__((ext_vector_type(4))) unsigned int   uint4v;

__device__ __forceinline__ unsigned short f2bf(float f) {
  unsigned int u = __float_as_uint(f);
  u += 0x7FFFu + ((u >> 16) & 1u);          // RNE
  return (unsigned short)(u >> 16);
}

__device__ __forceinline__ void dma16(const void* g, void* l) {
  __builtin_amdgcn_global_load_lds(
      (const __attribute__((address_space(1))) unsigned int*)g,
      (__attribute__((address_space(3))) unsigned int*)l, 16, 0, 0);
}

__device__ __forceinline__ float sig2(float x) {   // = (tanh(x)+1)/2 = sigma(2x)
  return __builtin_amdgcn_rcpf(1.f + __expf(-2.f * x));
}

// ---------------- prep 1: cast x -> bf16; zero flags ------------------------
__global__ void k_cast_x(const float* __restrict__ x, unsigned short* __restrict__ xb,
                         int* __restrict__ flags) {
  long i = ((long)blockIdx.x * 256 + threadIdx.x) * 8;
  f32x4 a = *(const f32x4*)(x + i);
  f32x4 b = *(const f32x4*)(x + i + 4);
  ushort8v o;
  o[0] = f2bf(a[0]); o[1] = f2bf(a[1]); o[2] = f2bf(a[2]); o[3] = f2bf(a[3]);
  o[4] = f2bf(b[0]); o[5] = f2bf(b[1]); o[6] = f2bf(b[2]); o[7] = f2bf(b[3]);
  *(ushort8v*)(xb + i) = o;
  if (blockIdx.x < 4) flags[(blockIdx.x << 8) + threadIdx.x] = 0;   // 1024 ints
}

// ---------------- prep 2: transpose-cast 8 x (1024x1024 fp32 -> [n][k] bf16)
__global__ void k_tcast8(const float* __restrict__ s0, const float* __restrict__ s1,
                         const float* __restrict__ s2, const float* __restrict__ s3,
                         const float* __restrict__ s4, const float* __restrict__ s5,
                         const float* __restrict__ s6, const float* __restrict__ s7,
                         unsigned short* __restrict__ dstBase) {
  __shared__ unsigned short tile[64][65];
  const int z = blockIdx.z;
  const float* src = (z == 0) ? s0 : (z == 1) ? s1 : (z == 2) ? s2 : (z == 3) ? s3
                   : (z == 4) ? s4 : (z == 5) ? s5 : (z == 6) ? s6 : s7;
  unsigned short* dst = dstBase + (size_t)z * 1048576;
  const int k0 = blockIdx.x << 6;
  const int n0 = blockIdx.y << 6;
  const int tid = threadIdx.x;
#pragma unroll
  for (int i = 0; i < 4; ++i) {
    int q = tid + (i << 8);
    int r = q >> 4, c4 = (q & 15) << 2;
    f32x4 v = *(const f32x4*)(src + (size_t)(k0 + r) * 1024 + n0 + c4);
    tile[r][c4 + 0] = f2bf(v[0]);
    tile[r][c4 + 1] = f2bf(v[1]);
    tile[r][c4 + 2] = f2bf(v[2]);
    tile[r][c4 + 3] = f2bf(v[3]);
  }
  __syncthreads();
#pragma unroll
  for (int i = 0; i < 4; ++i) {
    int q = tid + (i << 8);
    int rn = q >> 4, kc = (q & 15) << 2;
    ushort4v o;
    o[0] = tile[kc + 0][rn];
    o[1] = tile[kc + 1][rn];
    o[2] = tile[kc + 2][rn];
    o[3] = tile[kc + 3][rn];
    *(ushort4v*)(dst + (size_t)(n0 + rn) * 1024 + k0 + kc) = o;
  }
}

// coherent gather of 4 A-fragments (chunks K = wv+8*j4, +512B per +8 chunks);
// final vmcnt(0) also drains this wave's x-DMA for t+1 (wave-private Xs)
#define GATHER_WAIT(F0, F1, F2, F3, PB)                                  \
  asm volatile(                                                          \
      "global_load_dwordx4 %0, %4, off sc0 sc1\n\t"                      \
      "global_load_dwordx4 %1, %4, off offset:512 sc0 sc1\n\t"           \
      "global_load_dwordx4 %2, %4, off offset:1024 sc0 sc1\n\t"          \
      "global_load_dwordx4 %3, %4, off offset:1536 sc0 sc1\n\t"          \
      "s_waitcnt vmcnt(0)"                                               \
      : "=&v"(F0), "=&v"(F1), "=&v"(F2), "=&v"(F3)                       \
      : "v"(PB) : "memory")

// ---------------- main: persistent recurrence -------------------------------
__global__ __launch_bounds__(512, 2) void k_lstm(
    const unsigned short* __restrict__ xb,    // [512*64][1024] bf16
    const unsigned short* __restrict__ WtT,   // [4096][1024] bf16, n = gate*1024+u
    const unsigned short* __restrict__ RtT,
    const float* __restrict__ b_i, const float* __restrict__ b_f,
    const float* __restrict__ b_o, const float* __restrict__ b_c,
    const float* __restrict__ s0, const float* __restrict__ c0,
    unsigned int* __restrict__ hq,            // [4 bg][2 buf][16 row][512] dwords
    int* __restrict__ flags, float* __restrict__ out) {
  __shared__ __align__(16) unsigned short Xs[2][16384];   // 2 x 32 KB
  __shared__ __align__(16) float gl[8192];                // 32 KB (96 KB total)

  const int tid = threadIdx.x;
  const int bid = blockIdx.x;                 // 256 blocks = 4 bg x 64 cs
  const int cs = bid & 63;
  const int bg = bid >> 6;
  const int u0 = cs << 4;                     // 16 units
  const int b0 = bg << 4;                     // 16 batch rows
  const int wv = tid >> 6, ln = tid & 63;
  const int qd = ln >> 4, nc = ln & 15;
  const int grow = ln >> 2;                   // 0..15 (row for x-DMA)
  const int gsub = ln & 3;                    // 0..3  (global octet)
  const int gsx = gsub ^ (grow & 3);          // swizzled octet (Xs layout)

  // ---- weights: wave wv owns chunks K = j4*8 + wv, ALL 4 gates ----
  short8 wfr[4][4], rfr[4][4];
#pragma unroll
  for (int j4 = 0; j4 < 4; ++j4) {
    const int K = (j4 << 3) + wv;
#pragma unroll
    for (int g = 0; g < 4; ++g) {
      const size_t off = ((size_t)((g << 10) + u0 + nc) << 10) + (K << 5) + (qd << 3);
      wfr[j4][g] = *(const short8*)(WtT + off);
      rfr[j4][g] = *(const short8*)(RtT + off);
    }
  }

  // ---- per-thread state (tid<256): cell (m, un) ----
  const int m = tid >> 4, un = tid & 15;
  const int gio = (b0 + m) * 1024 + u0 + un;
  float c = 0.f, bi = 0.f, bff = 0.f, bo = 0.f, bc = 0.f;
  const int hq_bg = bg << 14;                 // dword base of this group's region
  if (tid < 256) {
    c = c0[gio];
    bi = b_i[u0 + un]; bff = b_f[u0 + un]; bo = b_o[u0 + un]; bc = b_c[u0 + un];
    float h0 = s0[gio];
    float hp = __shfl_xor(h0, 1);
    if (!(tid & 1)) {
      unsigned int wd = (unsigned int)f2bf(h0) | ((unsigned int)f2bf(hp) << 16);
      __hip_atomic_store(&hq[hq_bg + (m << 9) + ((u0 + un) >> 1)], wd,
                         __ATOMIC_RELAXED, __HIP_MEMORY_SCOPE_AGENT);
    }
  }
  // ---- stage x_0 (wave-private chunks; lds base is wave-uniform) ----
#pragma unroll
  for (int j4 = 0; j4 < 4; ++j4) {
    const int K = (j4 << 3) + wv;
    dma16(xb + (((size_t)(b0 + grow)) << 10) + (K << 5) + (gsx << 3), &Xs[0][K << 9]);
  }
  __syncthreads();                            // drains h0 stores + x0 DMA
  if (tid == 0)
    __hip_atomic_fetch_add(&flags[((bg << 3) + (bid & 7)) << 5], 1,
                           __ATOMIC_RELAXED, __HIP_MEMORY_SCOPE_AGENT);

  // per-lane fragment base: batch row nc, chunk wv(+8j4), octet qd
  const unsigned int* const pbE = hq + hq_bg + (nc << 9) + (wv << 4) + (qd << 2);
  const unsigned int* const pbO = pbE + 8192;
  // per-wave partial poll: this wave's producers have cs&7 in {2wv&7,(2wv+1)&7}
  int* const pollp = &flags[((bg << 3) + (((wv << 1) + (ln & 1)) & 7)) << 5];
  // gl swizzled read base (matches writer's rr^qd swizzle)
  const int rbase = (tid & 0xC0) + ((((tid >> 4) ^ (tid >> 6)) & 3) << 4) + (tid & 15);

  for (int t = 0; t < 512; ++t) {
    f32x4 acc[4] = {{0.f,0.f,0.f,0.f},{0.f,0.f,0.f,0.f},{0.f,0.f,0.f,0.f},{0.f,0.f,0.f,0.f}};
    // ---- x half (wave-private chunks) ----
    {
      const unsigned short* xsb = &Xs[t & 1][0];
#pragma unroll
      for (int j4 = 0; j4 < 4; ++j4) {
        const int K = (j4 << 3) + wv;
        short8 a = *(const short8*)(xsb + (K << 9) + (nc << 5) + ((qd ^ (nc & 3)) << 3));
#pragma unroll
        for (int g = 0; g < 4; ++g)
          acc[g] = __builtin_amdgcn_mfma_f32_16x16x32_bf16(a, wfr[j4][g], acc[g], 0, 0, 0);
      }
    }
    // ---- issue x_{t+1} DMA: drains during the poll, off the signal path ----
    {
      const int tn = (t + 1) & 511;
      const size_t xrow = (size_t)((tn << 6) + b0 + grow) << 10;
      unsigned short* xd = &Xs[(t + 1) & 1][0];
#pragma unroll
      for (int j4 = 0; j4 < 4; ++j4) {
        const int K = (j4 << 3) + wv;
        dma16(xb + xrow + (K << 5) + (gsx << 3), xd + (K << 9));
      }
    }
    // ---- per-wave poll on own producers only (flag layout/add unchanged) ----
    {
      const int target = (t + 1) << 3;
      while (__hip_atomic_load(pollp, __ATOMIC_RELAXED, __HIP_MEMORY_SCOPE_AGENT) < target)
        __builtin_amdgcn_s_sleep(1);
    }
    // ---- gather h_t directly as A-fragments (coherent, one trip) ----
    const unsigned int* pb = (t & 1) ? pbO : pbE;
    uint4v f0, f1, f2, f3;
    GATHER_WAIT(f0, f1, f2, f3, pb);
    // ---- h half (no Hs bounce) ----
    {
      short8 a0 = __builtin_bit_cast(short8, f0);
      short8 a1 = __builtin_bit_cast(short8, f1);
      short8 a2 = __builtin_bit_cast(short8, f2);
      short8 a3 = __builtin_bit_cast(short8, f3);
#pragma unroll
      for (int g = 0; g < 4; ++g) {
        acc[g] = __builtin_amdgcn_mfma_f32_16x16x32_bf16(a0, rfr[0][g], acc[g], 0, 0, 0);
        acc[g] = __builtin_amdgcn_mfma_f32_16x16x32_bf16(a1, rfr[1][g], acc[g], 0, 0, 0);
        acc[g] = __builtin_amdgcn_mfma_f32_16x16x32_bf16(a2, rfr[2][g], acc[g], 0, 0, 0);
        acc[g] = __builtin_amdgcn_mfma_f32_16x16x32_bf16(a3, rfr[3][g], acc[g], 0, 0, 0);
      }
      float* glw = &gl[wv << 10];
#pragma unroll
      for (int g = 0; g < 4; ++g)
#pragma unroll
        for (int rr = 0; rr < 4; ++rr)
          glw[(g << 8) + (qd << 6) + (((rr ^ qd) & 3) << 4) + nc] = acc[g][rr];
    }
    __syncthreads();                          // gl ready (syncA)
    // ---- gates, state update, publish h_{t+1} ----
    if (tid < 256) {
      float pi = bi, pfv = bff, po = bo, pc = bc;
      const float* glb = &gl[rbase];
#pragma unroll
      for (int w = 0; w < 8; ++w) {
        const float* glr = glb + (w << 10);
        pi += glr[0]; pfv += glr[256]; po += glr[512]; pc += glr[768];
      }
      float it = sig2(pi), ft = sig2(pfv), ot = sig2(po);
      float ch = 2.f * sig2(pc) - 1.f;
      c = ft * c + it * ch;
      float h = ot * (2.f * sig2(c) - 1.f);
      if (t < 511) {
        float hp = __shfl_xor(h, 1);
        if (!(tid & 1)) {
          unsigned int wd = (unsigned int)f2bf(h) | ((unsigned int)f2bf(hp) << 16);
          __hip_atomic_store(&hq[hq_bg + (((t + 1) & 1) << 13) + (m << 9) + ((u0 + un) >> 1)],
                             wd, __ATOMIC_RELAXED, __HIP_MEMORY_SCOPE_AGENT);
        }
      } else {
        out[gio] = h;
      }
    }
    __syncthreads();                          // h stores drained (syncB)
    if (tid == 0)
      __hip_atomic_fetch_add(&flags[((bg << 3) + (bid & 7)) << 5], 1,
                             __ATOMIC_RELAXED, __HIP_MEMORY_SCOPE_AGENT);
  }
}

// ---------------------------------------------------------------------------
extern "C" void kernel_launch(void* const* d_in, const int* in_sizes, int n_in,
                              void* d_out, int out_size, void* d_ws, size_t ws_size,
                              hipStream_t stream) {
  const float* x   = (const float*)d_in[0];
  const float* W_i = (const float*)d_in[1];
  const float* W_f = (const float*)d_in[2];
  const float* W_c = (const float*)d_in[3];
  const float* W_o = (const float*)d_in[4];
  const float* R_i = (const float*)d_in[5];
  const float* R_f = (const float*)d_in[6];
  const float* R_c = (const float*)d_in[7];
  const float* R_o = (const float*)d_in[8];
  const float* b_i = (const float*)d_in[9];
  const float* b_f = (const float*)d_in[10];
  const float* b_c = (const float*)d_in[11];
  const float* b_o = (const float*)d_in[12];
  const float* s0  = (const float*)d_in[13];
  const float* c0  = (const float*)d_in[14];
  float* out = (float*)d_out;

  char* ws = (char*)d_ws;
  unsigned short* xb  = (unsigned short*)(ws);                               // 64 MB
  unsigned short* WtT = (unsigned short*)(ws + (size_t)67108864);            // 8 MB
  unsigned short* RtT = (unsigned short*)(ws + (size_t)67108864 + 8388608);  // 8 MB
  unsigned int*   hq  = (unsigned int*)(ws + (size_t)67108864 + 16777216);   // 256 KB
  int* flags          = (int*)(ws + (size_t)67108864 + 16777216 + 262144);   // 4 KB

  k_cast_x<<<16384, 256, 0, stream>>>(x, xb, flags);
  // gate order i,f,o,c; z 0..3 -> W into WtT, z 4..7 -> R into RtT (contiguous)
  dim3 tg(16, 16, 8);
  k_tcast8<<<tg, 256, 0, stream>>>(W_i, W_f, W_o, W_c, R_i, R_f, R_o, R_c, WtT);

  k_lstm<<<256, 512, 0, stream>>>(xb, WtT, RtT, b_i, b_f, b_o, b_c, s0, c0,
                                  hq, flags, out);
}

// Round 4
// 1268.980 us; speedup vs baseline: 2.6000x; 1.2003x over previous
//
#include <hip/hip_runtime.h>

// ---------------------------------------------------------------------------
// LSTM layer, T=512 B=64 D=H=1024, out = h_T (64x1024 fp32).
// Round 9: r5 sync skeleton (load-bearing, unchanged) + fragment-major hq.
//   KEPT from round 5 (do NOT touch):
//     - syncA (gl ready) + syncB (h-store drain) per step
//     - coarse flags: 8 per group, 128B apart, ONE tid0 add per block/step
//     - FULL poll: lane ln polls flag ln&7 (r8's partial poll reverted)
//     - x-DMA issued before the poll; s_sleep(1) backoff
//   CHANGED vs r5:
//     A'. direct-fragment gather (no Hs LDS bounce) with a NEW fragment-major
//         hq layout: dword = bg*16384 + buf*8192 + K*256 + lane*4 + d,
//         lane = qd*16+nc (the consuming MFMA lane). Consumer loads are
//         lane-linear (64 lanes x 16B = 1KB contiguous per instruction).
//         r8's regression diagnosis: same gather in MFMA lane order
//         (row=ln&15) hit 16 distinct 64B lines per TA quarter-group -> 4x
//         L2 request amplification on the serial path. This layout fixes it.
//     B.  gl writes XOR-swizzled (rr^qd): conflict-free stores.
// ---------------------------------------------------------------------------

typedef __attribute__((ext_vector_type(8))) short     short8;   // 8 bf16 (4 VGPR)
typedef __attribute__((ext_vector_type(4))) float     f32x4;
typedef __attribute__((ext_vector_type(8))) unsigned short ushort8v;
typedef __attribute__((ext_vector_type(4))) unsigned short ushort4v;
typedef __attribute__((ext_vector_type(4))) unsigned int   uint4v;

__device__ __forceinline__ unsigned short f2bf(float f) {
  unsigned int u = __float_as_uint(f);
  u += 0x7FFFu + ((u >> 16) & 1u);          // RNE
  return (unsigned short)(u >> 16);
}

__device__ __forceinline__ void dma16(const void* g, void* l) {
  __builtin_amdgcn_global_load_lds(
      (const __attribute__((address_space(1))) unsigned int*)g,
      (__attribute__((address_space(3))) unsigned int*)l, 16, 0, 0);
}

__device__ __forceinline__ float sig2(float x) {   // = (tanh(x)+1)/2 = sigma(2x)
  return __builtin_amdgcn_rcpf(1.f + __expf(-2.f * x));
}

// ---------------- prep 1: cast x -> bf16; zero flags ------------------------
__global__ void k_cast_x(const float* __restrict__ x, unsigned short* __restrict__ xb,
                         int* __restrict__ flags) {
  long i = ((long)blockIdx.x * 256 + threadIdx.x) * 8;
  f32x4 a = *(const f32x4*)(x + i);
  f32x4 b = *(const f32x4*)(x + i + 4);
  ushort8v o;
  o[0] = f2bf(a[0]); o[1] = f2bf(a[1]); o[2] = f2bf(a[2]); o[3] = f2bf(a[3]);
  o[4] = f2bf(b[0]); o[5] = f2bf(b[1]); o[6] = f2bf(b[2]); o[7] = f2bf(b[3]);
  *(ushort8v*)(xb + i) = o;
  if (blockIdx.x < 4) flags[(blockIdx.x << 8) + threadIdx.x] = 0;   // 1024 ints
}

// ---------------- prep 2: transpose-cast 8 x (1024x1024 fp32 -> [n][k] bf16)
__global__ void k_tcast8(const float* __restrict__ s0, const float* __restrict__ s1,
                         const float* __restrict__ s2, const float* __restrict__ s3,
                         const float* __restrict__ s4, const float* __restrict__ s5,
                         const float* __restrict__ s6, const float* __restrict__ s7,
                         unsigned short* __restrict__ dstBase) {
  __shared__ unsigned short tile[64][65];
  const int z = blockIdx.z;
  const float* src = (z == 0) ? s0 : (z == 1) ? s1 : (z == 2) ? s2 : (z == 3) ? s3
                   : (z == 4) ? s4 : (z == 5) ? s5 : (z == 6) ? s6 : s7;
  unsigned short* dst = dstBase + (size_t)z * 1048576;
  const int k0 = blockIdx.x << 6;
  const int n0 = blockIdx.y << 6;
  const int tid = threadIdx.x;
#pragma unroll
  for (int i = 0; i < 4; ++i) {
    int q = tid + (i << 8);
    int r = q >> 4, c4 = (q & 15) << 2;
    f32x4 v = *(const f32x4*)(src + (size_t)(k0 + r) * 1024 + n0 + c4);
    tile[r][c4 + 0] = f2bf(v[0]);
    tile[r][c4 + 1] = f2bf(v[1]);
    tile[r][c4 + 2] = f2bf(v[2]);
    tile[r][c4 + 3] = f2bf(v[3]);
  }
  __syncthreads();
#pragma unroll
  for (int i = 0; i < 4; ++i) {
    int q = tid + (i << 8);
    int rn = q >> 4, kc = (q & 15) << 2;
    ushort4v o;
    o[0] = tile[kc + 0][rn];
    o[1] = tile[kc + 1][rn];
    o[2] = tile[kc + 2][rn];
    o[3] = tile[kc + 3][rn];
    *(ushort4v*)(dst + (size_t)(n0 + rn) * 1024 + k0 + kc) = o;
  }
}

// coherent gather of 4 A-fragments; addresses are lane-linear (ln*16B) per
// chunk. Final vmcnt(0) also drains this wave's x-DMA (wave-private Xs).
#define GATHER_WAIT(F0, F1, F2, F3, P0, P1, P2, P3)                      \
  asm volatile(                                                          \
      "global_load_dwordx4 %0, %4, off sc0 sc1\n\t"                      \
      "global_load_dwordx4 %1, %5, off sc0 sc1\n\t"                      \
      "global_load_dwordx4 %2, %6, off sc0 sc1\n\t"                      \
      "global_load_dwordx4 %3, %7, off sc0 sc1\n\t"                      \
      "s_waitcnt vmcnt(0)"                                               \
      : "=&v"(F0), "=&v"(F1), "=&v"(F2), "=&v"(F3)                       \
      : "v"(P0), "v"(P1), "v"(P2), "v"(P3)                               \
      : "memory")

// ---------------- main: persistent recurrence -------------------------------
__global__ __launch_bounds__(512, 2) void k_lstm(
    const unsigned short* __restrict__ xb,    // [512*64][1024] bf16
    const unsigned short* __restrict__ WtT,   // [4096][1024] bf16, n = gate*1024+u
    const unsigned short* __restrict__ RtT,
    const float* __restrict__ b_i, const float* __restrict__ b_f,
    const float* __restrict__ b_o, const float* __restrict__ b_c,
    const float* __restrict__ s0, const float* __restrict__ c0,
    unsigned int* __restrict__ hq,            // [4 bg][2 buf][32 K][64 lane][4] dw
    int* __restrict__ flags, float* __restrict__ out) {
  __shared__ __align__(16) unsigned short Xs[2][16384];   // 2 x 32 KB
  __shared__ __align__(16) float gl[8192];                // 32 KB (96 KB total)

  const int tid = threadIdx.x;
  const int bid = blockIdx.x;                 // 256 blocks = 4 bg x 64 cs
  const int cs = bid & 63;
  const int bg = bid >> 6;
  const int u0 = cs << 4;                     // 16 units
  const int b0 = bg << 4;                     // 16 batch rows
  const int wv = tid >> 6, ln = tid & 63;
  const int qd = ln >> 4, nc = ln & 15;
  const int grow = ln >> 2;                   // 0..15 (row for x-DMA)
  const int gsub = ln & 3;                    // 0..3  (global octet)
  const int gsx = gsub ^ (grow & 3);          // swizzled octet (Xs layout)

  // ---- weights: wave wv owns chunks K = j4*8 + wv, ALL 4 gates ----
  short8 wfr[4][4], rfr[4][4];
#pragma unroll
  for (int j4 = 0; j4 < 4; ++j4) {
    const int K = (j4 << 3) + wv;
#pragma unroll
    for (int g = 0; g < 4; ++g) {
      const size_t off = ((size_t)((g << 10) + u0 + nc) << 10) + (K << 5) + (qd << 3);
      wfr[j4][g] = *(const short8*)(WtT + off);
      rfr[j4][g] = *(const short8*)(RtT + off);
    }
  }

  // ---- per-thread state (tid<256): cell (m, un) ----
  const int m = tid >> 4, un = tid & 15;
  const int gio = (b0 + m) * 1024 + u0 + un;
  float c = 0.f, bi = 0.f, bff = 0.f, bo = 0.f, bc = 0.f;
  const int hq_bg = bg << 14;                 // dword base of this group's region
  // fragment-major producer slot: K=cs>>1, qd'=((cs&1)<<1)|(un>>3),
  // lane'=qd'*16+m, d=(un>>1)&3  (only even-un threads store)
  const int hw0 = hq_bg + ((cs >> 1) << 8) +
                  (((((cs & 1) << 1) | (un >> 3)) << 4) + m) * 4 + ((un >> 1) & 3);
  if (tid < 256) {
    c = c0[gio];
    bi = b_i[u0 + un]; bff = b_f[u0 + un]; bo = b_o[u0 + un]; bc = b_c[u0 + un];
    float h0 = s0[gio];
    float hp = __shfl_xor(h0, 1);
    if (!(tid & 1)) {                         // publish h_0 into buf 0
      unsigned int wd = (unsigned int)f2bf(h0) | ((unsigned int)f2bf(hp) << 16);
      __hip_atomic_store(&hq[hw0], wd, __ATOMIC_RELAXED, __HIP_MEMORY_SCOPE_AGENT);
    }
  }
  // ---- stage x_0 (wave-private chunks; lds base is wave-uniform) ----
#pragma unroll
  for (int j4 = 0; j4 < 4; ++j4) {
    const int K = (j4 << 3) + wv;
    dma16(xb + (((size_t)(b0 + grow)) << 10) + (K << 5) + (gsx << 3), &Xs[0][K << 9]);
  }
  __syncthreads();                            // drains h0 stores + x0 DMA
  if (tid == 0)
    __hip_atomic_fetch_add(&flags[((bg << 3) + (bid & 7)) << 5], 1,
                           __ATOMIC_RELAXED, __HIP_MEMORY_SCOPE_AGENT);

  // consumer gather bases: lane-linear. chunk K=wv+8*j4 at +j4*2048 dwords
  const unsigned int* const pbE = hq + hq_bg + (wv << 8) + (ln << 2);
  const unsigned int* const pbO = pbE + 8192;
  // full poll (r5): lane ln polls flag ln&7
  int* const pollp = &flags[((bg << 3) + (ln & 7)) << 5];
  // gl swizzled read base (matches writer's rr^qd swizzle)
  const int rbase = (tid & 0xC0) + ((((tid >> 4) ^ (tid >> 6)) & 3) << 4) + (tid & 15);

  for (int t = 0; t < 512; ++t) {
    f32x4 acc[4] = {{0.f,0.f,0.f,0.f},{0.f,0.f,0.f,0.f},{0.f,0.f,0.f,0.f},{0.f,0.f,0.f,0.f}};
    // ---- x half (wave-private chunks) ----
    {
      const unsigned short* xsb = &Xs[t & 1][0];
#pragma unroll
      for (int j4 = 0; j4 < 4; ++j4) {
        const int K = (j4 << 3) + wv;
        short8 a = *(const short8*)(xsb + (K << 9) + (nc << 5) + ((qd ^ (nc & 3)) << 3));
#pragma unroll
        for (int g = 0; g < 4; ++g)
          acc[g] = __builtin_amdgcn_mfma_f32_16x16x32_bf16(a, wfr[j4][g], acc[g], 0, 0, 0);
      }
    }
    // ---- issue x_{t+1} DMA: drains during the poll, off the signal path ----
    {
      const int tn = (t + 1) & 511;
      const size_t xrow = (size_t)((tn << 6) + b0 + grow) << 10;
      unsigned short* xd = &Xs[(t + 1) & 1][0];
#pragma unroll
      for (int j4 = 0; j4 < 4; ++j4) {
        const int K = (j4 << 3) + wv;
        dma16(xb + xrow + (K << 5) + (gsx << 3), xd + (K << 9));
      }
    }
    // ---- full poll on all 8 flags (r5 semantics) ----
    {
      const int target = (t + 1) << 3;
      while (__hip_atomic_load(pollp, __ATOMIC_RELAXED, __HIP_MEMORY_SCOPE_AGENT) < target)
        __builtin_amdgcn_s_sleep(1);
    }
    // ---- gather h_t directly as A-fragments (lane-linear, coherent) ----
    const unsigned int* pb = (t & 1) ? pbO : pbE;
    uint4v f0, f1, f2, f3;
    GATHER_WAIT(f0, f1, f2, f3, pb, pb + 2048, pb + 4096, pb + 6144);
    // ---- h half (no Hs bounce) ----
    {
      short8 a0 = __builtin_bit_cast(short8, f0);
      short8 a1 = __builtin_bit_cast(short8, f1);
      short8 a2 = __builtin_bit_cast(short8, f2);
      short8 a3 = __builtin_bit_cast(short8, f3);
#pragma unroll
      for (int g = 0; g < 4; ++g) {
        acc[g] = __builtin_amdgcn_mfma_f32_16x16x32_bf16(a0, rfr[0][g], acc[g], 0, 0, 0);
        acc[g] = __builtin_amdgcn_mfma_f32_16x16x32_bf16(a1, rfr[1][g], acc[g], 0, 0, 0);
        acc[g] = __builtin_amdgcn_mfma_f32_16x16x32_bf16(a2, rfr[2][g], acc[g], 0, 0, 0);
        acc[g] = __builtin_amdgcn_mfma_f32_16x16x32_bf16(a3, rfr[3][g], acc[g], 0, 0, 0);
      }
      float* glw = &gl[wv << 10];
#pragma unroll
      for (int g = 0; g < 4; ++g)
#pragma unroll
        for (int rr = 0; rr < 4; ++rr)
          glw[(g << 8) + (qd << 6) + (((rr ^ qd) & 3) << 4) + nc] = acc[g][rr];
    }
    __syncthreads();                          // gl ready (syncA)
    // ---- gates, state update, publish h_{t+1} ----
    if (tid < 256) {
      float pi = bi, pfv = bff, po = bo, pc = bc;
      const float* glb = &gl[rbase];
#pragma unroll
      for (int w = 0; w < 8; ++w) {
        const float* glr = glb + (w << 10);
        pi += glr[0]; pfv += glr[256]; po += glr[512]; pc += glr[768];
      }
      float it = sig2(pi), ft = sig2(pfv), ot = sig2(po);
      float ch = 2.f * sig2(pc) - 1.f;
      c = ft * c + it * ch;
      float h = ot * (2.f * sig2(c) - 1.f);
      if (t < 511) {
        float hp = __shfl_xor(h, 1);
        if (!(tid & 1)) {
          unsigned int wd = (unsigned int)f2bf(h) | ((unsigned int)f2bf(hp) << 16);
          __hip_atomic_store(&hq[hw0 + (((t + 1) & 1) << 13)], wd,
                             __ATOMIC_RELAXED, __HIP_MEMORY_SCOPE_AGENT);
        }
      } else {
        out[gio] = h;
      }
    }
    __syncthreads();                          // h stores drained (syncB)
    if (tid == 0)
      __hip_atomic_fetch_add(&flags[((bg << 3) + (bid & 7)) << 5], 1,
                             __ATOMIC_RELAXED, __HIP_MEMORY_SCOPE_AGENT);
  }
}

// ---------------------------------------------------------------------------
extern "C" void kernel_launch(void* const* d_in, const int* in_sizes, int n_in,
                              void* d_out, int out_size, void* d_ws, size_t ws_size,
                              hipStream_t stream) {
  const float* x   = (const float*)d_in[0];
  const float* W_i = (const float*)d_in[1];
  const float* W_f = (const float*)d_in[2];
  const float* W_c = (const float*)d_in[3];
  const float* W_o = (const float*)d_in[4];
  const float* R_i = (const float*)d_in[5];
  const float* R_f = (const float*)d_in[6];
  const float* R_c = (const float*)d_in[7];
  const float* R_o = (const float*)d_in[8];
  const float* b_i = (const float*)d_in[9];
  const float* b_f = (const float*)d_in[10];
  const float* b_c = (const float*)d_in[11];
  const float* b_o = (const float*)d_in[12];
  const float* s0  = (const float*)d_in[13];
  const float* c0  = (const float*)d_in[14];
  float* out = (float*)d_out;

  char* ws = (char*)d_ws;
  unsigned short* xb  = (unsigned short*)(ws);                               // 64 MB
  unsigned short* WtT = (unsigned short*)(ws + (size_t)67108864);            // 8 MB
  unsigned short* RtT = (unsigned short*)(ws + (size_t)67108864 + 8388608);  // 8 MB
  unsigned int*   hq  = (unsigned int*)(ws + (size_t)67108864 + 16777216);   // 256 KB
  int* flags          = (int*)(ws + (size_t)67108864 + 16777216 + 262144);   // 4 KB

  k_cast_x<<<16384, 256, 0, stream>>>(x, xb, flags);
  // gate order i,f,o,c; z 0..3 -> W into WtT, z 4..7 -> R into RtT (contiguous)
  dim3 tg(16, 16, 8);
  k_tcast8<<<tg, 256, 0, stream>>>(W_i, W_f, W_o, W_c, R_i, R_f, R_o, R_c, WtT);

  k_lstm<<<256, 512, 0, stream>>>(xb, WtT, RtT, b_i, b_f, b_o, b_c, s0, c0,
                                  hq, flags, out);
}